// Round 12
// baseline (420.229 us; speedup 1.0000x reference)
//
#include <hip/hip_runtime.h>
#include <math.h>

#define N_ 8
#define L_ 1024
#define H_ 16
#define E_ 1024
#define D_ 64

typedef __bf16 bf16x8 __attribute__((ext_vector_type(8)));
typedef __bf16 bf16x4 __attribute__((ext_vector_type(4)));
typedef float  f32x4  __attribute__((ext_vector_type(4)));

#define MFMA16(a, b, c) __builtin_amdgcn_mfma_f32_16x16x32_bf16((a), (b), (c), 0, 0, 0)

// exp(s/32) == exp2(s * KSCALE) with KSCALE folded into K at projection time.
#define KSCALE 0.04508422002778011f   // log2(e)/32

// ---------------------------------------------------------------------------
// prep: convert Wo (1M) and Erel (64K) f32 -> bf16 scratch.
// ---------------------------------------------------------------------------
__global__ __launch_bounds__(256) void prep_kernel(
    const float* __restrict__ Wo, const float* __restrict__ Erel,
    __bf16* __restrict__ wobf, __bf16* __restrict__ erbf)
{
    const int idx = blockIdx.x * 256 + threadIdx.x;
    const float* src;
    __bf16* dst;
    int off;
    if (blockIdx.x < 1024) { src = Wo;   dst = wobf; off = idx * 4; }
    else                   { src = Erel; dst = erbf; off = (idx - 1024 * 256) * 4; }
    const float4 f = *(const float4*)(src + off);
    bf16x4 h;
    h[0] = (__bf16)f.x; h[1] = (__bf16)f.y; h[2] = (__bf16)f.z; h[3] = (__bf16)f.w;
    *(bf16x4*)(dst + off) = h;
}

// ---------------------------------------------------------------------------
// qkv: one block per (n, h, 64-l tile). q,k written HEAD-MAJOR (n,h,l,d);
// v written TRANSPOSED (n,h,d,l) directly from the epilogue LDS transpose --
// this kills the separate vtr kernel. K pre-scaled by KSCALE.
// ---------------------------------------------------------------------------
__global__ __launch_bounds__(256) void qkv_kernel(
    const float* __restrict__ x,
    const float* __restrict__ Wq, const float* __restrict__ bq,
    const float* __restrict__ Wk, const float* __restrict__ bk,
    const float* __restrict__ Wv, const float* __restrict__ bv,
    __bf16* __restrict__ qo, __bf16* __restrict__ ko, __bf16* __restrict__ vto)
{
    const int bid = blockIdx.x;
    const int lt = bid & 15, h = (bid >> 4) & 15, n = bid >> 8;
    const int l0 = lt * 64;
    const int t = threadIdx.x, w = t >> 6, lane = t & 63;
    const int quad = lane >> 4, l16 = lane & 15;

    __shared__ __bf16 xs[64][72];        // x rows; reused for q epilogue
    __shared__ __bf16 wls[3][64][72];    // weights; [0]->k, [1]->v^T epilogue

    #pragma unroll
    for (int i = 0; i < 4; ++i) {
        const int idx = t + i * 256, row = idx >> 4, c4 = idx & 15;
        {
            const float4 f = *(const float4*)(
                x + ((size_t)(n * 1024 + l0 + row)) * 1024 + h * 64 + c4 * 4);
            bf16x4 hh; hh[0]=(__bf16)f.x; hh[1]=(__bf16)f.y; hh[2]=(__bf16)f.z; hh[3]=(__bf16)f.w;
            *(bf16x4*)&xs[row][c4 * 4] = hh;
        }
        {
            const float4 f = *(const float4*)(Wq + (size_t)row * 64 + c4 * 4);
            bf16x4 hh; hh[0]=(__bf16)f.x; hh[1]=(__bf16)f.y; hh[2]=(__bf16)f.z; hh[3]=(__bf16)f.w;
            *(bf16x4*)&wls[0][row][c4 * 4] = hh;
        }
        {
            const float4 f = *(const float4*)(Wk + (size_t)row * 64 + c4 * 4);
            bf16x4 hh; hh[0]=(__bf16)f.x; hh[1]=(__bf16)f.y; hh[2]=(__bf16)f.z; hh[3]=(__bf16)f.w;
            *(bf16x4*)&wls[1][row][c4 * 4] = hh;
        }
        {
            const float4 f = *(const float4*)(Wv + (size_t)row * 64 + c4 * 4);
            bf16x4 hh; hh[0]=(__bf16)f.x; hh[1]=(__bf16)f.y; hh[2]=(__bf16)f.z; hh[3]=(__bf16)f.w;
            *(bf16x4*)&wls[2][row][c4 * 4] = hh;
        }
    }
    __syncthreads();

    bf16x8 a[2];
    a[0] = *(const bf16x8*)&xs[w * 16 + l16][quad * 8];
    a[1] = *(const bf16x8*)&xs[w * 16 + l16][32 + quad * 8];

    f32x4 acc[12];
    const f32x4 zero4 = {0.f, 0.f, 0.f, 0.f};
    #pragma unroll
    for (int nt = 0; nt < 12; ++nt) acc[nt] = zero4;

    #pragma unroll
    for (int nt = 0; nt < 12; ++nt) {
        const int sel = nt >> 2, dt = nt & 3;
        #pragma unroll
        for (int c = 0; c < 2; ++c) {
            const bf16x8 b = *(const bf16x8*)&wls[sel][dt * 16 + l16][c * 32 + quad * 8];
            acc[nt] = MFMA16(a[c], b, acc[nt]);
        }
    }
    __syncthreads();   // all LDS reads done -> reuse xs / wls[0] / wls[1]

    // epilogue: q -> xs[m][d], k -> wls[0][m][d] (scaled), v^T -> wls[1][d][m]
    #pragma unroll
    for (int nt = 0; nt < 12; ++nt) {
        const int sel = nt >> 2, dt = nt & 3;
        const int dcol = dt * 16 + l16;
        if (sel == 0) {
            const float bb = bq[dcol];
            #pragma unroll
            for (int r = 0; r < 4; ++r)
                xs[w * 16 + quad * 4 + r][dcol] = (__bf16)(acc[nt][r] + bb);
        } else if (sel == 1) {
            const float bb = bk[dcol];
            #pragma unroll
            for (int r = 0; r < 4; ++r)
                wls[0][w * 16 + quad * 4 + r][dcol] =
                    (__bf16)((acc[nt][r] + bb) * KSCALE);
        } else {
            const float bb = bv[dcol];
            #pragma unroll
            for (int r = 0; r < 4; ++r)
                wls[1][dcol][w * 16 + quad * 4 + r] = (__bf16)(acc[nt][r] + bb);
        }
    }
    __syncthreads();

    // coalesced dumps: q,k rows = l (head-major); v^T rows = d
    const size_t qkBase = ((size_t)(n * 16 + h) * 1024 + l0) * 64;
    const size_t vBase  = ((size_t)(n * 16 + h) * 64) * 1024 + l0;
    #pragma unroll
    for (int i = 0; i < 2; ++i) {
        const int idx = t * 2 + i, row = idx >> 3, c = idx & 7;
        *(float4*)(qo + qkBase + (size_t)row * 64 + c * 8) =
            *(const float4*)&xs[row][c * 8];
        *(float4*)(ko + qkBase + (size_t)row * 64 + c * 8) =
            *(const float4*)&wls[0][row][c * 8];
        *(float4*)(vto + vBase + (size_t)row * 1024 + c * 8) =
            *(const float4*)&wls[1][row][c * 8];
    }
}

// ---------------------------------------------------------------------------
// attn (merged flash+rel, r6 double-buffer skeleton + merged PV):
// out = softmax(QK^T/32)@V + skew(QErel^T,masked)@V. 512 thr / 8 waves, 128 q
// rows per block, 16 q/wave. One barrier per k-tile (dbuf); register-prefetch
// two tiles ahead. K head-major (contiguous 8KB tile), V pre-transposed.
//
// LAUNCH BOUNDS LESSON (r5/r9/r10): (512, N) acts as min BLOCKS/CU -> N=4
// caps VGPR at 64 and this body peaks ~80 live -> GB-scale scratch spill
// (WRITE_SIZE tripwire). N=3 -> cap ~85; merged body compiled at 84 (r11).
// r11 lesson: single-buffer (2 barriers/kt) regressed 178->241 us; keep dbuf.
// ---------------------------------------------------------------------------
__global__ __launch_bounds__(512, 3) void attn_kernel(
    const __bf16* __restrict__ qbf, const __bf16* __restrict__ kbf,
    const __bf16* __restrict__ vtrb, const __bf16* __restrict__ erbf,
    __bf16* __restrict__ attnA)
{
    const int bid = blockIdx.x;
    // p bits {0-2,6-9}: bid%8 stable per (n,h) -> XCD L2 reuse; qt descending
    const int p  = (bid & 7) | ((bid >> 6) << 3);
    const int qt = 7 - ((bid >> 3) & 7);
    const int h = p & 15, n = p >> 4;
    const int q0 = qt * 128;
    const int t = threadIdx.x, w = t >> 6, lane = t & 63;
    const int quad = lane >> 4, l16 = lane & 15;

    __shared__ __bf16 ks[2][64][72];   // K tile (key, d)
    __shared__ __bf16 vt[2][64][72];   // V^T tile (d, key)
    __shared__ __bf16 ps[128][72];     // exp-P / rel scatter / epilogue

    const int qw0 = q0 + w * 16;
    const __bf16* qrow = qbf + ((size_t)(n * 16 + h) * 1024 + qw0 + l16) * 64;
    const bf16x8 qa0 = *(const bf16x8*)(qrow + quad * 8);
    const bf16x8 qa1 = *(const bf16x8*)(qrow + 32 + quad * 8);

    const __bf16* kbase = kbf + (size_t)(n * 16 + h) * 65536;   // (l, d) rows
    const __bf16* vbase = vtrb + (size_t)(n * 16 + h) * 65536;  // (d, l) rows
    const int srow = t >> 3, sc8 = (t & 7) * 8;   // one float4 per thread each

    // tile 0 -> buf 0; tile 1 -> regs
    float4 kreg = *(const float4*)(kbase + (size_t)srow * 64 + sc8);
    float4 vreg = *(const float4*)(vbase + (size_t)srow * 1024 + sc8);
    *(float4*)&ks[0][srow][sc8] = kreg;
    *(float4*)&vt[0][srow][sc8] = vreg;
    kreg = *(const float4*)(kbase + 4096 + (size_t)srow * 64 + sc8);
    vreg = *(const float4*)(vbase + 64 + (size_t)srow * 1024 + sc8);
    __syncthreads();

    const f32x4 zero4 = {0.f, 0.f, 0.f, 0.f};
    f32x4 Os[4], Or[4];
    #pragma unroll
    for (int nt = 0; nt < 4; ++nt) { Os[nt] = zero4; Or[nt] = zero4; }
    float esum = 0.f;

    for (int kt = 0; kt < 16; ++kt) {
        const int cur = kt & 1;
        if (kt < 15) {
            // tile kt+1 (in regs) -> idle buffer; its readers finished before
            // the barrier at the end of iteration kt-1.
            *(float4*)&ks[cur ^ 1][srow][sc8] = kreg;
            *(float4*)&vt[cur ^ 1][srow][sc8] = vreg;
            if (kt < 14) {   // issue loads for kt+2; a full iteration to land
                kreg = *(const float4*)(kbase + (size_t)(kt + 2) * 4096
                                        + (size_t)srow * 64 + sc8);
                vreg = *(const float4*)(vbase + (kt + 2) * 64
                                        + (size_t)srow * 1024 + sc8);
            }
        }

        // ---- S'^T = K' Q^T (K pre-scaled by log2e/32) ----
        f32x4 sc[4];
        #pragma unroll
        for (int nt = 0; nt < 4; ++nt) {
            f32x4 acc = zero4;
            acc = MFMA16(*(const bf16x8*)&ks[cur][nt * 16 + l16][quad * 8], qa0, acc);
            acc = MFMA16(*(const bf16x8*)&ks[cur][nt * 16 + l16][32 + quad * 8], qa1, acc);
            sc[nt] = acc;
        }

        // ---- fixed-base exp + deferred lsum; pack exp-P to ps ----
        #pragma unroll
        for (int nt = 0; nt < 4; ++nt) {
            bf16x4 pk;
            #pragma unroll
            for (int r = 0; r < 4; ++r) {
                const float e = exp2f(sc[nt][r]);
                esum += e;
                pk[r] = (__bf16)e;
            }
            *(bf16x4*)&ps[w * 16 + l16][nt * 16 + quad * 4] = pk;
        }
        const bf16x8 pb0 = *(const bf16x8*)&ps[w * 16 + l16][quad * 8];
        const bf16x8 pb1 = *(const bf16x8*)&ps[w * 16 + l16][32 + quad * 8];

        // ---- rel scores: QE strips, skew-scatter into the SAME ps rows ----
        const bool dorel = (kt * 64 <= qw0 + 15);
        bf16x8 rb0{}, rb1{};
        if (dorel) {
            const int tb = kt * 64 + 1008 - qw0;   // >= 0 always
            #pragma unroll
            for (int st = 0; st < 5; ++st) {
                int tr = tb + st * 16 + l16;
                tr = tr > 1023 ? 1023 : tr;        // clamped rows masked below
                const __bf16* er = erbf + (size_t)tr * 64;
                f32x4 acc = zero4;
                acc = MFMA16(*(const bf16x8*)(er + quad * 8), qa0, acc);
                acc = MFMA16(*(const bf16x8*)(er + 32 + quad * 8), qa1, acc);
                // skew scatter: k-col = st*16+quad*4+r+l16-15, mask t>1023
                #pragma unroll
                for (int r = 0; r < 4; ++r) {
                    const int kc = st * 16 + quad * 4 + r + l16 - 15;
                    const int tg = tb + st * 16 + quad * 4 + r;
                    if (kc >= 0 && kc < 64)
                        ps[w * 16 + l16][kc] = (tg <= 1023) ? (__bf16)acc[r]
                                                            : (__bf16)0.0f;
                }
            }
            rb0 = *(const bf16x8*)&ps[w * 16 + l16][quad * 8];
            rb1 = *(const bf16x8*)&ps[w * 16 + l16][32 + quad * 8];
        }

        // ---- merged PV: each V^T frag read once for Os (and Or if rel) ----
        #pragma unroll
        for (int nt = 0; nt < 4; ++nt) {
            const bf16x8 va0 = *(const bf16x8*)&vt[cur][nt * 16 + l16][quad * 8];
            const bf16x8 va1 = *(const bf16x8*)&vt[cur][nt * 16 + l16][32 + quad * 8];
            Os[nt] = MFMA16(va0, pb0, Os[nt]);
            Os[nt] = MFMA16(va1, pb1, Os[nt]);
            if (dorel) {
                Or[nt] = MFMA16(va0, rb0, Or[nt]);
                Or[nt] = MFMA16(va1, rb1, Or[nt]);
            }
        }
        __syncthreads();   // the single per-iteration barrier
    }

    // ---- epilogue: one cross-lane lsum reduce, assemble in ps, b128 stores --
    esum += __shfl_xor(esum, 16, 64);
    esum += __shfl_xor(esum, 32, 64);
    const float invl = 1.0f / esum;
    #pragma unroll
    for (int nt = 0; nt < 4; ++nt) {
        bf16x4 ov;
        #pragma unroll
        for (int r = 0; r < 4; ++r)
            ov[r] = (__bf16)(Os[nt][r] * invl + Or[nt][r]);
        *(bf16x4*)&ps[w * 16 + l16][nt * 16 + quad * 4] = ov;
    }
    const int erow = lane >> 3, ec8 = lane & 7;
    #pragma unroll
    for (int i = 0; i < 2; ++i) {
        const int r = erow + i * 8;
        const float4 val = *(const float4*)&ps[w * 16 + r][ec8 * 8];
        *(float4*)(attnA + ((size_t)(n * L_ + qw0 + r)) * E_ + h * 64 + ec8 * 8) = val;
    }
}

// ---------------------------------------------------------------------------
// proj: out (8192 x 1024) f32 = attnA (bf16) @ Wo^T (bf16) + bo.
// 128x128 C tile, BK=64, global_load_lds width-16 staging.
// ---------------------------------------------------------------------------
__global__ __launch_bounds__(256) void proj_kernel(
    const __bf16* __restrict__ A, const __bf16* __restrict__ W,
    const float* __restrict__ bo, float* __restrict__ out)
{
    const int bid = blockIdx.x;
    const int rt = bid >> 3, ct = bid & 7;
    const int r0 = rt * 128, c0 = ct * 128;
    const int t = threadIdx.x, w = t >> 6, lane = t & 63;
    const int quad = lane >> 4, l16 = lane & 15;
    const int wm = w >> 1, wn = w & 1;

    __shared__ __bf16 As[128 * 64];
    __shared__ __bf16 Bs[128 * 64];

    f32x4 acc[16];
    const f32x4 zero4 = {0.f, 0.f, 0.f, 0.f};
    #pragma unroll
    for (int i = 0; i < 16; ++i) acc[i] = zero4;

    const int lrow = lane >> 3, lcg = lane & 7;

    for (int kt = 0; kt < 16; ++kt) {
        const int e0 = kt * 64;
        __syncthreads();
        #pragma unroll
        for (int i = 0; i < 4; ++i) {
            const int chunk = w * 4 + i;
            const int row = chunk * 8 + lrow;
            const __bf16* ga = A + (size_t)(r0 + row) * E_ + e0 + lcg * 8;
            const __bf16* gb = W + (size_t)(c0 + row) * E_ + e0 + lcg * 8;
            __builtin_amdgcn_global_load_lds(
                (const __attribute__((address_space(1))) void*)ga,
                (__attribute__((address_space(3))) void*)&As[chunk * 512], 16, 0, 0);
            __builtin_amdgcn_global_load_lds(
                (const __attribute__((address_space(1))) void*)gb,
                (__attribute__((address_space(3))) void*)&Bs[chunk * 512], 16, 0, 0);
        }
        __syncthreads();
        #pragma unroll
        for (int c = 0; c < 2; ++c) {
            bf16x8 am[4], bn[4];
            #pragma unroll
            for (int i = 0; i < 4; ++i) {
                am[i] = *(const bf16x8*)&As[(wm * 64 + i * 16 + l16) * 64 + c * 32 + quad * 8];
                bn[i] = *(const bf16x8*)&Bs[(wn * 64 + i * 16 + l16) * 64 + c * 32 + quad * 8];
            }
            #pragma unroll
            for (int i = 0; i < 4; ++i)
                #pragma unroll
                for (int j = 0; j < 4; ++j)
                    acc[i * 4 + j] = MFMA16(am[i], bn[j], acc[i * 4 + j]);
        }
    }

    #pragma unroll
    for (int i = 0; i < 4; ++i)
        #pragma unroll
        for (int j = 0; j < 4; ++j) {
            const int col = c0 + wn * 64 + j * 16 + l16;
            const float bb = bo[col];
            #pragma unroll
            for (int r = 0; r < 4; ++r)
                out[(size_t)(r0 + wm * 64 + i * 16 + quad * 4 + r) * E_ + col] =
                    acc[i * 4 + j][r] + bb;
        }
}

// ---------------------------------------------------------------------------
extern "C" void kernel_launch(void* const* d_in, const int* in_sizes, int n_in,
                              void* d_out, int out_size, void* d_ws, size_t ws_size,
                              hipStream_t stream)
{
    const float* x    = (const float*)d_in[0];
    const float* Wq   = (const float*)d_in[1];
    const float* bq   = (const float*)d_in[2];
    const float* Wk   = (const float*)d_in[3];
    const float* bk   = (const float*)d_in[4];
    const float* Wv   = (const float*)d_in[5];
    const float* bv   = (const float*)d_in[6];
    const float* Erel = (const float*)d_in[7];
    const float* Wo   = (const float*)d_in[8];
    const float* bo   = (const float*)d_in[9];
    float* out = (float*)d_out;

    char* p = (char*)d_ws;
    __bf16* qbf   = (__bf16*)p; p += (size_t)N_ * L_ * H_ * D_ * 2;  // (n,h,l,d)
    __bf16* kbf   = (__bf16*)p; p += (size_t)N_ * L_ * H_ * D_ * 2;  // scaled, (n,h,l,d)
    __bf16* vtrb  = (__bf16*)p; p += (size_t)N_ * L_ * H_ * D_ * 2;  // (n,h,d,l)
    __bf16* attnA = (__bf16*)p; p += (size_t)N_ * L_ * E_ * 2;       // (n,l,E)
    __bf16* wobf  = (__bf16*)p; p += (size_t)E_ * E_ * 2;
    __bf16* erbf  = (__bf16*)p; p += (size_t)L_ * D_ * 2;

    prep_kernel<<<1088, 256, 0, stream>>>(Wo, Erel, wobf, erbf);
    qkv_kernel<<<N_ * H_ * (L_ / 64), 256, 0, stream>>>(x, Wq, bq, Wk, bk, Wv, bv,
                                                        qbf, kbf, vtrb);
    attn_kernel<<<N_ * H_ * (L_ / 128), 512, 0, stream>>>(qbf, kbf, vtrb, erbf, attnA);
    proj_kernel<<<(N_ * L_ / 128) * (E_ / 128), 256, 0, stream>>>(attnA, wobf, bo, out);
}